// Round 7
// baseline (1131.109 us; speedup 1.0000x reference)
//
#include <hip/hip_runtime.h>
#include <stdint.h>

// ---------------------------------------------------------------------------
// torch-ngp hashgrid encode (16 levels, dim 2) + 32->64->8 ReLU MLP, 8-corner
// trilinear blend.  One thread per (point, outer corner); 8 threads/point are
// consecutive lanes -> shuffle reduction + coalesced store.
//
// R7: revert to the R2 anchor (335us: pure-VALU MLP, no LDS, (256,6), VGPR 40,
// clean WRITE_SIZE) -- the R4-R6 MFMA detour loses: unified VGPR+AGPR demand
// (~104 regs) caps occupancy at 4 blocks/CU and any higher wave target spills
// catastrophically (R5: 1.1GB scratch, R6: 630MB).
//
// R7 change vs R2: MLP inner products issued as v_pk_fma_f32 (VOP3P, 2xf32
// per issue slot).  Pairs: h[k],h[k+1] vs SGPR weight pair (legal single-SGPR
// VOP3P operand); fi broadcast as {fi,fi}.  Two independent IEEE FMAs per
// inst, same accumulation order as R2 -> BIT-IDENTICAL results (absmax must
// read 0.000488).  MLP instr count: 2560 fma -> ~1280 pk + ~256 movs.
// Tripwire: WRITE_SIZE must stay 8192KB (spills); else drop to (256,5).
// ---------------------------------------------------------------------------

#define BLK 256
#define R15 513

typedef float f32x2 __attribute__((ext_vector_type(2)));

// d = a * b + d, packed 2xf32.  b comes from wave-uniform memory -> SGPR pair
// (VOP3P allows one SGPR-pair operand).  a is a VGPR pair, d a VGPR pair.
__device__ __forceinline__ void pk_fma_sv(f32x2& d, const f32x2 a, const f32x2 b) {
    asm("v_pk_fma_f32 %0, %1, %2, %0" : "+v"(d) : "v"(a), "s"(b));
}

// Linear (tight-grid) level: compile-time R/H/O so % H becomes magic-multiply.
template <int R, int H, int O>
__device__ __forceinline__ void enc_linear(float xcx, float xcy, float xcz,
                                           const float2* __restrict__ tab,
                                           float& f0, float& f1) {
    const float Rf = (float)R;
    // replicate reference op order: pos = x*R + 0.5 (no fma contraction)
    float px = __fadd_rn(__fmul_rn(xcx, Rf), 0.5f);
    float py = __fadd_rn(__fmul_rn(xcy, Rf), 0.5f);
    float pz = __fadd_rn(__fmul_rn(xcz, Rf), 0.5f);
    float fpx = floorf(px), fpy = floorf(py), fpz = floorf(pz);
    float frx = px - fpx, fry = py - fpy, frz = pz - fpz;
    int gx = (int)fpx, gy = (int)fpy, gz = (int)fpz;
    float wx[2] = {1.f - frx, frx};
    float wy[2] = {1.f - fry, fry};
    float wz[2] = {1.f - frz, frz};
    const int R1 = R + 1;
    int xt[2] = {gx, gx + 1};
    int yt[2] = {gy * R1, gy * R1 + R1};
    int zt[2] = {gz * R1 * R1, gz * R1 * R1 + R1 * R1};
    float a0 = 0.f, a1 = 0.f;
#pragma unroll
    for (int c = 0; c < 8; ++c) {  // corner order (x,y,z) = bits (2,1,0): matches CORNERS
        const int ox = (c >> 2) & 1, oy = (c >> 1) & 1, oz = c & 1;
        int id  = xt[ox] + yt[oy] + zt[oz];
        int idx = (int)((uint32_t)id % (uint32_t)H);  // reference applies % H even on tight grids
        float w = wx[ox] * wy[oy] * wz[oz];
        float2 tv = tab[O + idx];
        a0 = fmaf(w, tv.x, a0);
        a1 = fmaf(w, tv.y, a1);
    }
    f0 = a0; f1 = a1;
}

// Hashed level (H = 2^19): compile-time R/O, hand-CSE'd hash terms.
template <int RI, int O>
__device__ __forceinline__ void enc_hash(float xcx, float xcy, float xcz,
                                         const float2* __restrict__ tab,
                                         float& f0, float& f1) {
    const float Rf = (float)RI;
    float px = __fadd_rn(__fmul_rn(xcx, Rf), 0.5f);
    float py = __fadd_rn(__fmul_rn(xcy, Rf), 0.5f);
    float pz = __fadd_rn(__fmul_rn(xcz, Rf), 0.5f);
    float fpx = floorf(px), fpy = floorf(py), fpz = floorf(pz);
    float frx = px - fpx, fry = py - fpy, frz = pz - fpz;
    uint32_t gx = (uint32_t)(int)fpx, gy = (uint32_t)(int)fpy, gz = (uint32_t)(int)fpz;
    float wx[2] = {1.f - frx, frx};
    float wy[2] = {1.f - fry, fry};
    float wz[2] = {1.f - frz, frz};
    // instant-NGP fast_hash primes {1, 2654435761, 805459861}; CSE the 8 muls
    uint32_t xt[2] = {gx, gx + 1u};
    uint32_t yt[2] = {gy * 2654435761u, gy * 2654435761u + 2654435761u};
    uint32_t zt[2] = {gz * 805459861u,  gz * 805459861u  + 805459861u};
    float a0 = 0.f, a1 = 0.f;
#pragma unroll
    for (int c = 0; c < 8; ++c) {
        const int ox = (c >> 2) & 1, oy = (c >> 1) & 1, oz = c & 1;
        uint32_t idx = (xt[ox] ^ yt[oy] ^ zt[oz]) & 524287u;
        float w = wx[ox] * wy[oy] * wz[oz];
        float2 tv = tab[O + (int)idx];
        a0 = fmaf(w, tv.x, a0);
        a1 = fmaf(w, tv.y, a1);
    }
    f0 = a0; f1 = a1;
}

__global__ __launch_bounds__(BLK, 6)
void grid_fused(const float* __restrict__ xyz, const float* __restrict__ bound,
                const float* __restrict__ table, const float* __restrict__ w1,
                const float* __restrict__ w2, float* __restrict__ out, int N) {
    const int tid = threadIdx.x;
    const int t = blockIdx.x * BLK + tid;
    const int p = t >> 3;
    const int a = t & 7;
    if (p >= N) return;

    const float2* tab = (const float2*)table;

    const float b = bound[0];
    float X = xyz[3 * p + 0], Y = xyz[3 * p + 1], Z = xyz[3 * p + 2];
    // x = (xyz + bound) / (2*bound); coords = x * 512
    float cx = ((X + b) / (2.0f * b)) * 512.0f;
    float cy = ((Y + b) / (2.0f * b)) * 512.0f;
    float cz = ((Z + b) / (2.0f * b)) * 512.0f;
    float c0x = fmaxf(fminf(floorf(cx), 511.f), 0.f);
    float c0y = fmaxf(fminf(floorf(cy), 511.f), 0.f);
    float c0z = fmaxf(fminf(floorf(cz), 511.f), 0.f);
    float uu = cx - c0x, vv = cy - c0y, wwf = cz - c0z;  // outer trilinear fracs

    const int ax = (a >> 2) & 1, ay = (a >> 1) & 1, az = a & 1;  // CORNERS order
    // encode-space coordinate of this outer corner: (c0+a)/512, exact
    float xcx = (c0x + (float)ax) * (1.0f / 512.0f);
    float xcy = (c0y + (float)ay) * (1.0f / 512.0f);
    float xcz = (c0z + (float)az) * (1.0f / 512.0f);

    // ---- all 16 levels -> 32 feature registers (bit-identical encode) ------
    float fr[32];
    enc_linear<16,   4920,      0>(xcx, xcy, xcz, tab, fr[ 0], fr[ 1]);
    enc_linear<21,  10648,   4920>(xcx, xcy, xcz, tab, fr[ 2], fr[ 3]);
    enc_linear<26,  19688,  15568>(xcx, xcy, xcz, tab, fr[ 4], fr[ 5]);
    enc_linear<33,  39304,  35256>(xcx, xcy, xcz, tab, fr[ 6], fr[ 7]);
    enc_linear<41,  74088,  74560>(xcx, xcy, xcz, tab, fr[ 8], fr[ 9]);
    enc_linear<51, 140608, 148648>(xcx, xcy, xcz, tab, fr[10], fr[11]);
    enc_linear<65, 287496, 289256>(xcx, xcy, xcz, tab, fr[12], fr[13]);
    enc_hash< 81,  576752>(xcx, xcy, xcz, tab, fr[14], fr[15]);
    enc_hash<102, 1101040>(xcx, xcy, xcz, tab, fr[16], fr[17]);
    enc_hash<129, 1625328>(xcx, xcy, xcz, tab, fr[18], fr[19]);
    enc_hash<162, 2149616>(xcx, xcy, xcz, tab, fr[20], fr[21]);
    enc_hash<204, 2673904>(xcx, xcy, xcz, tab, fr[22], fr[23]);
    enc_hash<257, 3198192>(xcx, xcy, xcz, tab, fr[24], fr[25]);
    enc_hash<324, 3722480>(xcx, xcy, xcz, tab, fr[26], fr[27]);
    enc_hash<408, 4246768>(xcx, xcy, xcz, tab, fr[28], fr[29]);
    enc_hash<R15, 4771056>(xcx, xcy, xcz, tab, fr[30], fr[31]);

    // ---- MLP: relu(feats @ w1) @ w2 via v_pk_fma_f32 (2xf32/issue) ---------
    // h pairs (h[k],h[k+1]) accumulate against SGPR weight pairs; fi broadcast
    // as {fi,fi}.  Same accumulation order as the scalar R2 version ->
    // bit-identical results.  hidden dim in four 16-unit chunks (8 pairs).
    f32x2 acc2[4] = {{0.f, 0.f}, {0.f, 0.f}, {0.f, 0.f}, {0.f, 0.f}};
#pragma unroll 1
    for (int kb = 0; kb < 64; kb += 16) {
        f32x2 h2[8];
#pragma unroll
        for (int kp = 0; kp < 8; ++kp) h2[kp] = (f32x2){0.f, 0.f};
#pragma unroll
        for (int i = 0; i < 32; ++i) {
            const f32x2 fi2 = {fr[i], fr[i]};
            const f32x2* wr2 = (const f32x2*)(w1 + i * 64 + kb);  // uniform -> s_load
#pragma unroll
            for (int kp = 0; kp < 8; ++kp) pk_fma_sv(h2[kp], fi2, wr2[kp]);
        }
#pragma unroll
        for (int k = 0; k < 16; ++k) {
            float hk = fmaxf(h2[k >> 1][k & 1], 0.f);
            const f32x2 hk2 = {hk, hk};
            const f32x2* w2r2 = (const f32x2*)(w2 + (kb + k) * 8);  // uniform -> s_load
#pragma unroll
            for (int jp = 0; jp < 4; ++jp) pk_fma_sv(acc2[jp], hk2, w2r2[jp]);
        }
    }

    // ---- outer trilinear weight + 8-lane reduction --------------------------
    float o[8];
#pragma unroll
    for (int j = 0; j < 8; ++j) o[j] = acc2[j >> 1][j & 1];

    float wt = (ax ? uu : 1.f - uu) * (ay ? vv : 1.f - vv) * (az ? wwf : 1.f - wwf);
#pragma unroll
    for (int j = 0; j < 8; ++j) {
        float v = o[j] * wt;
        v += __shfl_xor(v, 1);
        v += __shfl_xor(v, 2);
        v += __shfl_xor(v, 4);
        o[j] = v;  // all 8 lanes now hold the full sum for output j
    }
    // lane a writes output column a -> out[p*8 + a] == out[t], fully coalesced
    float r01 = (a & 1) ? o[1] : o[0];
    float r23 = (a & 1) ? o[3] : o[2];
    float r45 = (a & 1) ? o[5] : o[4];
    float r67 = (a & 1) ? o[7] : o[6];
    float r03 = (a & 2) ? r23 : r01;
    float r47 = (a & 2) ? r67 : r45;
    float r   = (a & 4) ? r47 : r03;
    out[t] = r;
}

extern "C" void kernel_launch(void* const* d_in, const int* in_sizes, int n_in,
                              void* d_out, int out_size, void* d_ws, size_t ws_size,
                              hipStream_t stream) {
    const float* xyz   = (const float*)d_in[0];
    const float* bound = (const float*)d_in[1];
    const float* table = (const float*)d_in[2];
    const float* w1    = (const float*)d_in[3];
    const float* w2    = (const float*)d_in[4];
    float* out = (float*)d_out;

    const int N = in_sizes[0] / 3;          // 262144
    const int threads = N * 8;              // one thread per (point, corner)
    const int blocks = (threads + BLK - 1) / BLK;
    grid_fused<<<blocks, BLK, 0, stream>>>(xyz, bound, table, w1, w2, out, N);
}

// Round 8
// 402.400 us; speedup vs baseline: 2.8109x; 2.8109x over previous
//
#include <hip/hip_runtime.h>
#include <stdint.h>

// ---------------------------------------------------------------------------
// torch-ngp hashgrid encode (16 levels, dim 2) + 32->64->8 ReLU MLP, 8-corner
// trilinear blend.  One thread per (point, outer corner); 8 threads/point are
// consecutive lanes -> shuffle reduction + coalesced store.
//
// R8 = R2 anchor (335us; VGPR 40, occ 61%, VALUBusy 71%, clean WRITE_SIZE)
// with the MLP issued as v_dot2_f32_f16 (f16 pair multiplies, f32 accumulate)
// via __builtin_amdgcn_fdot2 -- NO inline asm, NO register-class pinning
// (R7's "s"-constraint pinned 256 SGPR pairs -> 680MB spill storm).
//  * weights pre-paired (half2 over the reduction axis) into d_ws by a tiny
//    prep kernel; main-kernel weight stream stays uniform s_loads like R2.
//  * MLP math: 2048+512 v_fmac -> 1024+256 dot2 + ~150 cvt.
//  * expected absmax ~1-2e-3 (f16 inputs, f32 accum); R4-R6 passed 1.95e-3.
// Tripwires: WRITE_SIZE must stay 8192KB, FETCH ~1.13GB; absmax < thresh.
// ---------------------------------------------------------------------------

#define BLK 256
#define R15 513

typedef _Float16 half2v __attribute__((ext_vector_type(2)));

// Linear (tight-grid) level: compile-time R/H/O so % H becomes magic-multiply.
template <int R, int H, int O>
__device__ __forceinline__ void enc_linear(float xcx, float xcy, float xcz,
                                           const float2* __restrict__ tab,
                                           float& f0, float& f1) {
    const float Rf = (float)R;
    // replicate reference op order: pos = x*R + 0.5 (no fma contraction)
    float px = __fadd_rn(__fmul_rn(xcx, Rf), 0.5f);
    float py = __fadd_rn(__fmul_rn(xcy, Rf), 0.5f);
    float pz = __fadd_rn(__fmul_rn(xcz, Rf), 0.5f);
    float fpx = floorf(px), fpy = floorf(py), fpz = floorf(pz);
    float frx = px - fpx, fry = py - fpy, frz = pz - fpz;
    int gx = (int)fpx, gy = (int)fpy, gz = (int)fpz;
    float wx[2] = {1.f - frx, frx};
    float wy[2] = {1.f - fry, fry};
    float wz[2] = {1.f - frz, frz};
    const int R1 = R + 1;
    int xt[2] = {gx, gx + 1};
    int yt[2] = {gy * R1, gy * R1 + R1};
    int zt[2] = {gz * R1 * R1, gz * R1 * R1 + R1 * R1};
    float a0 = 0.f, a1 = 0.f;
#pragma unroll
    for (int c = 0; c < 8; ++c) {  // corner order (x,y,z) = bits (2,1,0): matches CORNERS
        const int ox = (c >> 2) & 1, oy = (c >> 1) & 1, oz = c & 1;
        int id  = xt[ox] + yt[oy] + zt[oz];
        int idx = (int)((uint32_t)id % (uint32_t)H);  // reference applies % H even on tight grids
        float w = wx[ox] * wy[oy] * wz[oz];
        float2 tv = tab[O + idx];
        a0 = fmaf(w, tv.x, a0);
        a1 = fmaf(w, tv.y, a1);
    }
    f0 = a0; f1 = a1;
}

// Hashed level (H = 2^19): compile-time R/O, hand-CSE'd hash terms.
template <int RI, int O>
__device__ __forceinline__ void enc_hash(float xcx, float xcy, float xcz,
                                         const float2* __restrict__ tab,
                                         float& f0, float& f1) {
    const float Rf = (float)RI;
    float px = __fadd_rn(__fmul_rn(xcx, Rf), 0.5f);
    float py = __fadd_rn(__fmul_rn(xcy, Rf), 0.5f);
    float pz = __fadd_rn(__fmul_rn(xcz, Rf), 0.5f);
    float fpx = floorf(px), fpy = floorf(py), fpz = floorf(pz);
    float frx = px - fpx, fry = py - fpy, frz = pz - fpz;
    uint32_t gx = (uint32_t)(int)fpx, gy = (uint32_t)(int)fpy, gz = (uint32_t)(int)fpz;
    float wx[2] = {1.f - frx, frx};
    float wy[2] = {1.f - fry, fry};
    float wz[2] = {1.f - frz, frz};
    // instant-NGP fast_hash primes {1, 2654435761, 805459861}; CSE the 8 muls
    uint32_t xt[2] = {gx, gx + 1u};
    uint32_t yt[2] = {gy * 2654435761u, gy * 2654435761u + 2654435761u};
    uint32_t zt[2] = {gz * 805459861u,  gz * 805459861u  + 805459861u};
    float a0 = 0.f, a1 = 0.f;
#pragma unroll
    for (int c = 0; c < 8; ++c) {
        const int ox = (c >> 2) & 1, oy = (c >> 1) & 1, oz = c & 1;
        uint32_t idx = (xt[ox] ^ yt[oy] ^ zt[oz]) & 524287u;
        float w = wx[ox] * wy[oy] * wz[oz];
        float2 tv = tab[O + (int)idx];
        a0 = fmaf(w, tv.x, a0);
        a1 = fmaf(w, tv.y, a1);
    }
    f0 = a0; f1 = a1;
}

// ---- prep: pack weights into half2 pairs over the reduction axis ----------
// ws[0..1023]   : w1p[ip*64 + k] = {w1[2ip][k], w1[2ip+1][k]}   (ip<16, k<64)
// ws[1024..1279]: w2p[kp*8  + j] = {w2[2kp][j], w2[2kp+1][j]}   (kp<32, j<8)
__global__ void pack_weights(const float* __restrict__ w1,
                             const float* __restrict__ w2,
                             uint32_t* __restrict__ ws) {
    int idx = blockIdx.x * blockDim.x + threadIdx.x;
    float a, b;
    if (idx < 1024) {
        int ip = idx >> 6, k = idx & 63;
        a = w1[(2 * ip) * 64 + k];
        b = w1[(2 * ip + 1) * 64 + k];
    } else if (idx < 1280) {
        int r = idx - 1024;
        int kp = r >> 3, j = r & 7;
        a = w2[(2 * kp) * 8 + j];
        b = w2[(2 * kp + 1) * 8 + j];
    } else {
        return;
    }
    half2v h = {(_Float16)a, (_Float16)b};  // RTE converts
    ws[idx] = *(const uint32_t*)&h;
}

__global__ __launch_bounds__(BLK, 6)
void grid_fused(const float* __restrict__ xyz, const float* __restrict__ bound,
                const float* __restrict__ table, const uint32_t* __restrict__ wsp,
                float* __restrict__ out, int N) {
    const int tid = threadIdx.x;
    const int t = blockIdx.x * BLK + tid;
    const int p = t >> 3;
    const int a = t & 7;
    if (p >= N) return;

    const float2* tab = (const float2*)table;

    const float b = bound[0];
    float X = xyz[3 * p + 0], Y = xyz[3 * p + 1], Z = xyz[3 * p + 2];
    // x = (xyz + bound) / (2*bound); coords = x * 512
    float cx = ((X + b) / (2.0f * b)) * 512.0f;
    float cy = ((Y + b) / (2.0f * b)) * 512.0f;
    float cz = ((Z + b) / (2.0f * b)) * 512.0f;
    float c0x = fmaxf(fminf(floorf(cx), 511.f), 0.f);
    float c0y = fmaxf(fminf(floorf(cy), 511.f), 0.f);
    float c0z = fmaxf(fminf(floorf(cz), 511.f), 0.f);
    float uu = cx - c0x, vv = cy - c0y, wwf = cz - c0z;  // outer trilinear fracs

    const int ax = (a >> 2) & 1, ay = (a >> 1) & 1, az = a & 1;  // CORNERS order
    // encode-space coordinate of this outer corner: (c0+a)/512, exact
    float xcx = (c0x + (float)ax) * (1.0f / 512.0f);
    float xcy = (c0y + (float)ay) * (1.0f / 512.0f);
    float xcz = (c0z + (float)az) * (1.0f / 512.0f);

    // ---- all 16 levels -> 32 feature registers (bit-identical encode) ------
    float fr[32];
    enc_linear<16,   4920,      0>(xcx, xcy, xcz, tab, fr[ 0], fr[ 1]);
    enc_linear<21,  10648,   4920>(xcx, xcy, xcz, tab, fr[ 2], fr[ 3]);
    enc_linear<26,  19688,  15568>(xcx, xcy, xcz, tab, fr[ 4], fr[ 5]);
    enc_linear<33,  39304,  35256>(xcx, xcy, xcz, tab, fr[ 6], fr[ 7]);
    enc_linear<41,  74088,  74560>(xcx, xcy, xcz, tab, fr[ 8], fr[ 9]);
    enc_linear<51, 140608, 148648>(xcx, xcy, xcz, tab, fr[10], fr[11]);
    enc_linear<65, 287496, 289256>(xcx, xcy, xcz, tab, fr[12], fr[13]);
    enc_hash< 81,  576752>(xcx, xcy, xcz, tab, fr[14], fr[15]);
    enc_hash<102, 1101040>(xcx, xcy, xcz, tab, fr[16], fr[17]);
    enc_hash<129, 1625328>(xcx, xcy, xcz, tab, fr[18], fr[19]);
    enc_hash<162, 2149616>(xcx, xcy, xcz, tab, fr[20], fr[21]);
    enc_hash<204, 2673904>(xcx, xcy, xcz, tab, fr[22], fr[23]);
    enc_hash<257, 3198192>(xcx, xcy, xcz, tab, fr[24], fr[25]);
    enc_hash<324, 3722480>(xcx, xcy, xcz, tab, fr[26], fr[27]);
    enc_hash<408, 4246768>(xcx, xcy, xcz, tab, fr[28], fr[29]);
    enc_hash<R15, 4771056>(xcx, xcy, xcz, tab, fr[30], fr[31]);

    // ---- pack feats into 16 half2 pairs (RTE casts, frees fr afterwards) ---
    half2v fp[16];
#pragma unroll
    for (int ip = 0; ip < 16; ++ip)
        fp[ip] = (half2v){(_Float16)fr[2 * ip], (_Float16)fr[2 * ip + 1]};

    const half2v* w1p = (const half2v*)wsp;          // [ip*64 + k]
    const half2v* w2p = (const half2v*)(wsp + 1024); // [kp*8 + j]

    // ---- MLP: relu(feats @ w1) @ w2 via v_dot2_f32_f16 (f32 accumulate) ----
    // weight addresses depend only on loop indices -> wave-uniform s_loads,
    // same codegen shape as R2.  No asm; compiler owns operand placement.
    float acc[8] = {0.f, 0.f, 0.f, 0.f, 0.f, 0.f, 0.f, 0.f};
#pragma unroll 1
    for (int kb = 0; kb < 64; kb += 16) {
        float h[16];
#pragma unroll
        for (int k = 0; k < 16; ++k) h[k] = 0.f;
#pragma unroll
        for (int ip = 0; ip < 16; ++ip) {
#pragma unroll
            for (int k = 0; k < 16; ++k)
                h[k] = __builtin_amdgcn_fdot2(fp[ip], w1p[ip * 64 + kb + k], h[k], false);
        }
        // relu + pack hidden pairs, then layer-2 dot2s for this chunk
        half2v hp[8];
#pragma unroll
        for (int kp = 0; kp < 8; ++kp)
            hp[kp] = (half2v){(_Float16)fmaxf(h[2 * kp], 0.f),
                              (_Float16)fmaxf(h[2 * kp + 1], 0.f)};
#pragma unroll
        for (int kp = 0; kp < 8; ++kp) {
            const int kpg = (kb >> 1) + kp;  // global hidden-pair index
#pragma unroll
            for (int j = 0; j < 8; ++j)
                acc[j] = __builtin_amdgcn_fdot2(hp[kp], w2p[kpg * 8 + j], acc[j], false);
        }
    }

    // ---- outer trilinear weight + 8-lane reduction --------------------------
    float wt = (ax ? uu : 1.f - uu) * (ay ? vv : 1.f - vv) * (az ? wwf : 1.f - wwf);
#pragma unroll
    for (int j = 0; j < 8; ++j) {
        float v = acc[j] * wt;
        v += __shfl_xor(v, 1);
        v += __shfl_xor(v, 2);
        v += __shfl_xor(v, 4);
        acc[j] = v;  // all 8 lanes now hold the full sum for output j
    }
    // lane a writes output column a -> out[p*8 + a] == out[t], fully coalesced
    float r01 = (a & 1) ? acc[1] : acc[0];
    float r23 = (a & 1) ? acc[3] : acc[2];
    float r45 = (a & 1) ? acc[5] : acc[4];
    float r67 = (a & 1) ? acc[7] : acc[6];
    float r03 = (a & 2) ? r23 : r01;
    float r47 = (a & 2) ? r67 : r45;
    float r   = (a & 4) ? r47 : r03;
    out[t] = r;
}

extern "C" void kernel_launch(void* const* d_in, const int* in_sizes, int n_in,
                              void* d_out, int out_size, void* d_ws, size_t ws_size,
                              hipStream_t stream) {
    const float* xyz   = (const float*)d_in[0];
    const float* bound = (const float*)d_in[1];
    const float* table = (const float*)d_in[2];
    const float* w1    = (const float*)d_in[3];
    const float* w2    = (const float*)d_in[4];
    float* out = (float*)d_out;
    uint32_t* ws = (uint32_t*)d_ws;   // needs 1280 * 4 B = 5 KB

    const int N = in_sizes[0] / 3;          // 262144
    pack_weights<<<5, 256, 0, stream>>>(w1, w2, ws);

    const int threads = N * 8;              // one thread per (point, corner)
    const int blocks = (threads + BLK - 1) / BLK;
    grid_fused<<<blocks, BLK, 0, stream>>>(xyz, bound, table, ws, out, N);
}